// Round 6
// baseline (31.212 us; speedup 1.0000x reference)
//
#include <hip/hip_runtime.h>
#include <math.h>

#define DT    0.019999999552965164f
#define GRAV  9.8100004196167f
#define GEAR  100.0f

typedef float vfloat4 __attribute__((ext_vector_type(4)));

__device__ __forceinline__ void rk4_one(
    float x0, float v0, float t0, float o0, float F,
    float b, float d, float M, float m2l, float Ieff, float m2gl, float IeffM,
    vfloat4& r)
{
    auto deriv = [&](float v_, float t_, float o_, float& xdd, float& tdd) {
        float s, c;
        __sincosf(t_, &s, &c);
        float A    = F - b * v_ + m2l * o_ * o_ * s;
        float Bq   = m2gl * s - d * o_;
        float mlc  = m2l * c;
        float D    = IeffM - mlc * mlc;
        float invD = __builtin_amdgcn_rcpf(D);
        xdd = (Ieff * A - mlc * Bq) * invD;
        tdd = (M * Bq - mlc * A) * invD;
    };

    const float half = 0.5f * DT;

    float k1v, k1o;
    deriv(v0, t0, o0, k1v, k1o);

    float v2 = v0 + half * k1v;
    float t2 = t0 + half * o0;
    float o2 = o0 + half * k1o;
    float k2v, k2o;
    deriv(v2, t2, o2, k2v, k2o);

    float v3 = v0 + half * k2v;
    float t3 = t0 + half * o2;
    float o3 = o0 + half * k2o;
    float k3v, k3o;
    deriv(v3, t3, o3, k3v, k3o);

    float v4 = v0 + DT * k3v;
    float t4 = t0 + DT * o3;
    float o4 = o0 + DT * k3o;
    float k4v, k4o;
    deriv(v4, t4, o4, k4v, k4o);

    const float w = DT * (1.0f / 6.0f);
    r.x = x0 + w * (v0  + 2.0f * v2  + 2.0f * v3  + v4);
    r.y = v0 + w * (k1v + 2.0f * k2v + 2.0f * k3v + k4v);
    r.z = t0 + w * (o0  + 2.0f * o2  + 2.0f * o3  + o4);
    r.w = o0 + w * (k1o + 2.0f * k2o + 2.0f * k3o + k4o);
}

// 256 threads x 4 elements each = 1024 elements/block.
// Loads: float4 (16B/lane). Results staged through LDS so the global stores
// are lane-contiguous 16B/lane (the R2 known-good pattern, no write
// amplification like the direct 64B-stride stores of R3).
__global__ __launch_bounds__(256) void cartpole_rk4_kernel(
    const float* __restrict__ x,
    const float* __restrict__ v,
    const float* __restrict__ th,
    const float* __restrict__ om,
    const float* __restrict__ u,
    const float* __restrict__ pI,
    const float* __restrict__ pb,
    const float* __restrict__ pd,
    const float* __restrict__ pl,
    const float* __restrict__ pm1,
    const float* __restrict__ pm2,
    vfloat4* __restrict__ out,
    int n)
{
    __shared__ vfloat4 sm[1024];

    const float I  = pI[0];
    const float b  = pb[0];
    const float d  = pd[0];
    const float l  = pl[0];
    const float m1 = pm1[0];
    const float m2 = pm2[0];

    const float M     = m1 + m2;
    const float m2l   = m2 * l;
    const float Ieff  = I + m2l * l;
    const float m2gl  = m2l * GRAV;
    const float IeffM = Ieff * M;

    const int tid  = threadIdx.x;
    const int base = blockIdx.x * 1024;
    const int i0   = base + tid * 4;

    if (base + 1023 < n) {
        const vfloat4 xv = *reinterpret_cast<const vfloat4*>(x  + i0);
        const vfloat4 vv = *reinterpret_cast<const vfloat4*>(v  + i0);
        const vfloat4 tv = *reinterpret_cast<const vfloat4*>(th + i0);
        const vfloat4 ov = *reinterpret_cast<const vfloat4*>(om + i0);
        const vfloat4 uv = *reinterpret_cast<const vfloat4*>(u  + i0);

        vfloat4 r0, r1, r2, r3;
        rk4_one(xv.x, vv.x, tv.x, ov.x, GEAR * uv.x, b, d, M, m2l, Ieff, m2gl, IeffM, r0);
        rk4_one(xv.y, vv.y, tv.y, ov.y, GEAR * uv.y, b, d, M, m2l, Ieff, m2gl, IeffM, r1);
        rk4_one(xv.z, vv.z, tv.z, ov.z, GEAR * uv.z, b, d, M, m2l, Ieff, m2gl, IeffM, r2);
        rk4_one(xv.w, vv.w, tv.w, ov.w, GEAR * uv.w, b, d, M, m2l, Ieff, m2gl, IeffM, r3);

        // sm[k*256 + s] holds the result for element base + 4*s + k.
        // Write: 16B/lane lane-contiguous -> conflict-free.
        sm[0 * 256 + tid] = r0;
        sm[1 * 256 + tid] = r1;
        sm[2 * 256 + tid] = r2;
        sm[3 * 256 + tid] = r3;

        __syncthreads();

        // Read element e = 256*j + tid from sm[(e&3)*256 + (e>>2)], store
        // lane-contiguous: out[base + 256*j + tid].
#pragma unroll
        for (int j = 0; j < 4; ++j) {
            int e = 256 * j + tid;
            vfloat4 r = sm[(e & 3) * 256 + (e >> 2)];
            out[base + e] = r;
        }
    } else {
        // scalar tail (not hit for B = 4M, but keep it correct generally)
        for (int i = i0; i < n && i < i0 + 4; ++i) {
            vfloat4 r;
            rk4_one(x[i], v[i], th[i], om[i], GEAR * u[i],
                    b, d, M, m2l, Ieff, m2gl, IeffM, r);
            out[i] = r;
        }
    }
}

extern "C" void kernel_launch(void* const* d_in, const int* in_sizes, int n_in,
                              void* d_out, int out_size, void* d_ws, size_t ws_size,
                              hipStream_t stream) {
    const float* x   = (const float*)d_in[0];
    const float* v   = (const float*)d_in[1];
    const float* th  = (const float*)d_in[2];
    const float* om  = (const float*)d_in[3];
    const float* u   = (const float*)d_in[4];
    const float* pI  = (const float*)d_in[5];
    const float* pb  = (const float*)d_in[6];
    const float* pd  = (const float*)d_in[7];
    const float* pl  = (const float*)d_in[8];
    const float* pm1 = (const float*)d_in[9];
    const float* pm2 = (const float*)d_in[10];

    int n = in_sizes[0];  // B = 4194304
    vfloat4* out = (vfloat4*)d_out;

    int block = 256;
    int elems_per_block = block * 4;
    int grid = (n + elems_per_block - 1) / elems_per_block;
    cartpole_rk4_kernel<<<grid, block, 0, stream>>>(
        x, v, th, om, u, pI, pb, pd, pl, pm1, pm2, out, n);
}

// Round 7
// 29.765 us; speedup vs baseline: 1.0486x; 1.0486x over previous
//
#include <hip/hip_runtime.h>
#include <math.h>

#define DT    0.019999999552965164f
#define GRAV  9.8100004196167f
#define GEAR  100.0f

typedef float vfloat4 __attribute__((ext_vector_type(4)));

__global__ __launch_bounds__(256) void cartpole_rk4_kernel(
    const float* __restrict__ x,
    const float* __restrict__ v,
    const float* __restrict__ th,
    const float* __restrict__ om,
    const float* __restrict__ u,
    const float* __restrict__ pI,
    const float* __restrict__ pb,
    const float* __restrict__ pd,
    const float* __restrict__ pl,
    const float* __restrict__ pm1,
    const float* __restrict__ pm2,
    vfloat4* __restrict__ out,
    int n)
{
    // uniform physical parameters
    const float I  = pI[0];
    const float b  = pb[0];
    const float d  = pd[0];
    const float l  = pl[0];
    const float m1 = pm1[0];
    const float m2 = pm2[0];

    const float M     = m1 + m2;
    const float m2l   = m2 * l;
    const float Ieff  = I + m2l * l;        // I + m2*l*l
    const float m2gl  = m2l * GRAV;         // m2*g*l
    const float IeffM = Ieff * M;

    const float half = 0.5f * DT;
    const float w    = DT * (1.0f / 6.0f);

    const int stride = gridDim.x * blockDim.x;

    // Grid-stride: each wave gets n/stride (=8 at B=4M, grid=2048x256)
    // independent iterations -> compiler pipelines next iteration's 5 loads
    // under this iteration's sincos/rcp chain. Load/store per-instruction
    // patterns identical to the known-good R2 kernel.
    for (int i = blockIdx.x * blockDim.x + threadIdx.x; i < n; i += stride) {
        const float x0 = x[i];
        const float v0 = v[i];
        const float t0 = th[i];
        const float o0 = om[i];
        const float F  = GEAR * u[i];

        auto deriv = [&](float v_, float t_, float o_, float& xdd, float& tdd) {
            float s, c;
            __sincosf(t_, &s, &c);
            float A    = F - b * v_ + m2l * o_ * o_ * s;
            float Bq   = m2gl * s - d * o_;
            float mlc  = m2l * c;
            float D    = IeffM - mlc * mlc;
            float invD = __builtin_amdgcn_rcpf(D);
            xdd = (Ieff * A - mlc * Bq) * invD;
            tdd = (M * Bq - mlc * A) * invD;
        };

        float k1v, k1o;
        deriv(v0, t0, o0, k1v, k1o);

        float v2 = v0 + half * k1v;
        float t2 = t0 + half * o0;
        float o2 = o0 + half * k1o;
        float k2v, k2o;
        deriv(v2, t2, o2, k2v, k2o);

        float v3 = v0 + half * k2v;
        float t3 = t0 + half * o2;
        float o3 = o0 + half * k2o;
        float k3v, k3o;
        deriv(v3, t3, o3, k3v, k3o);

        float v4 = v0 + DT * k3v;
        float t4 = t0 + DT * o3;
        float o4 = o0 + DT * k3o;
        float k4v, k4o;
        deriv(v4, t4, o4, k4v, k4o);

        vfloat4 r;
        r.x = x0 + w * (v0  + 2.0f * v2  + 2.0f * v3  + v4);
        r.y = v0 + w * (k1v + 2.0f * k2v + 2.0f * k3v + k4v);
        r.z = t0 + w * (o0  + 2.0f * o2  + 2.0f * o3  + o4);
        r.w = o0 + w * (k1o + 2.0f * k2o + 2.0f * k3o + k4o);

        out[i] = r;
    }
}

extern "C" void kernel_launch(void* const* d_in, const int* in_sizes, int n_in,
                              void* d_out, int out_size, void* d_ws, size_t ws_size,
                              hipStream_t stream) {
    const float* x   = (const float*)d_in[0];
    const float* v   = (const float*)d_in[1];
    const float* th  = (const float*)d_in[2];
    const float* om  = (const float*)d_in[3];
    const float* u   = (const float*)d_in[4];
    const float* pI  = (const float*)d_in[5];
    const float* pb  = (const float*)d_in[6];
    const float* pd  = (const float*)d_in[7];
    const float* pl  = (const float*)d_in[8];
    const float* pm1 = (const float*)d_in[9];
    const float* pm2 = (const float*)d_in[10];

    int n = in_sizes[0];  // B = 4194304
    vfloat4* out = (vfloat4*)d_out;

    int block = 256;
    // Cap the grid (Guideline 11): 2048 blocks = 8 blocks/CU; each thread
    // grid-strides over 8 elements.
    int grid = (n + block - 1) / block;
    if (grid > 2048) grid = 2048;
    cartpole_rk4_kernel<<<grid, block, 0, stream>>>(
        x, v, th, om, u, pI, pb, pd, pl, pm1, pm2, out, n);
}

// Round 11
// 28.309 us; speedup vs baseline: 1.1025x; 1.0514x over previous
//
#include <hip/hip_runtime.h>
#include <math.h>

#define DT    0.019999999552965164f
#define GRAV  9.8100004196167f
#define GEAR  100.0f

typedef float vfloat4 __attribute__((ext_vector_type(4)));

__global__ __launch_bounds__(256) void cartpole_rk4_kernel(
    const float* __restrict__ x,
    const float* __restrict__ v,
    const float* __restrict__ th,
    const float* __restrict__ om,
    const float* __restrict__ u,
    const float* __restrict__ pI,
    const float* __restrict__ pb,
    const float* __restrict__ pd,
    const float* __restrict__ pl,
    const float* __restrict__ pm1,
    const float* __restrict__ pm2,
    vfloat4* __restrict__ out,
    int n)
{
    // uniform physical parameters
    const float I  = pI[0];
    const float b  = pb[0];
    const float d  = pd[0];
    const float l  = pl[0];
    const float m1 = pm1[0];
    const float m2 = pm2[0];

    const float M     = m1 + m2;
    const float m2l   = m2 * l;
    const float Ieff  = I + m2l * l;        // I + m2*l*l
    const float m2gl  = m2l * GRAV;         // m2*g*l
    const float IeffM = Ieff * M;

    const float half = 0.5f * DT;
    const float w    = DT * (1.0f / 6.0f);

    const int hn = n >> 1;                   // n is even (B = 4M)
    const int t  = blockIdx.x * blockDim.x + threadIdx.x;
    if (t >= hn) return;

    const int iA = t;        // stream A
    const int iB = t + hn;   // stream B — independent, same coalescing per instr

    // issue all 10 loads up front (2x MLP of the one-element kernel)
    const float xA = x[iA],  xB = x[iB];
    const float vA = v[iA],  vB = v[iB];
    const float tA = th[iA], tB = th[iB];
    const float oA = om[iA], oB = om[iB];
    const float FA = GEAR * u[iA], FB = GEAR * u[iB];

    auto deriv = [&](float F, float v_, float t_, float o_, float& xdd, float& tdd) {
        float s, c;
        __sincosf(t_, &s, &c);
        float A    = F - b * v_ + m2l * o_ * o_ * s;
        float Bq   = m2gl * s - d * o_;
        float mlc  = m2l * c;
        float D    = IeffM - mlc * mlc;
        float invD = __builtin_amdgcn_rcpf(D);
        xdd = (Ieff * A - mlc * Bq) * invD;
        tdd = (M * Bq - mlc * A) * invD;
    };

    // two interleaved independent RK4 chains (ILP=2 on the serial
    // sincos->rcp dependency chain)
    float k1vA, k1oA, k1vB, k1oB;
    deriv(FA, vA, tA, oA, k1vA, k1oA);
    deriv(FB, vB, tB, oB, k1vB, k1oB);

    float v2A = vA + half * k1vA,  v2B = vB + half * k1vB;
    float t2A = tA + half * oA,    t2B = tB + half * oB;
    float o2A = oA + half * k1oA,  o2B = oB + half * k1oB;
    float k2vA, k2oA, k2vB, k2oB;
    deriv(FA, v2A, t2A, o2A, k2vA, k2oA);
    deriv(FB, v2B, t2B, o2B, k2vB, k2oB);

    float v3A = vA + half * k2vA,  v3B = vB + half * k2vB;
    float t3A = tA + half * o2A,   t3B = tB + half * o2B;
    float o3A = oA + half * k2oA,  o3B = oB + half * k2oB;
    float k3vA, k3oA, k3vB, k3oB;
    deriv(FA, v3A, t3A, o3A, k3vA, k3oA);
    deriv(FB, v3B, t3B, o3B, k3vB, k3oB);

    float v4A = vA + DT * k3vA,  v4B = vB + DT * k3vB;
    float t4A = tA + DT * o3A,   t4B = tB + DT * o3B;
    float o4A = oA + DT * k3oA,  o4B = oB + DT * k3oB;
    float k4vA, k4oA, k4vB, k4oB;
    deriv(FA, v4A, t4A, o4A, k4vA, k4oA);
    deriv(FB, v4B, t4B, o4B, k4vB, k4oB);

    vfloat4 rA;
    rA.x = xA + w * (vA   + 2.0f * v2A  + 2.0f * v3A  + v4A);
    rA.y = vA + w * (k1vA + 2.0f * k2vA + 2.0f * k3vA + k4vA);
    rA.z = tA + w * (oA   + 2.0f * o2A  + 2.0f * o3A  + o4A);
    rA.w = oA + w * (k1oA + 2.0f * k2oA + 2.0f * k3oA + k4oA);

    vfloat4 rB;
    rB.x = xB + w * (vB   + 2.0f * v2B  + 2.0f * v3B  + v4B);
    rB.y = vB + w * (k1vB + 2.0f * k2vB + 2.0f * k3vB + k4vB);
    rB.z = tB + w * (oB   + 2.0f * o2B  + 2.0f * o3B  + o4B);
    rB.w = oB + w * (k1oB + 2.0f * k2oB + 2.0f * k3oB + k4oB);

    // both stores lane-contiguous 16B/lane (the known-good pattern)
    out[iA] = rA;
    out[iB] = rB;
}

extern "C" void kernel_launch(void* const* d_in, const int* in_sizes, int n_in,
                              void* d_out, int out_size, void* d_ws, size_t ws_size,
                              hipStream_t stream) {
    const float* x   = (const float*)d_in[0];
    const float* v   = (const float*)d_in[1];
    const float* th  = (const float*)d_in[2];
    const float* om  = (const float*)d_in[3];
    const float* u   = (const float*)d_in[4];
    const float* pI  = (const float*)d_in[5];
    const float* pb  = (const float*)d_in[6];
    const float* pd  = (const float*)d_in[7];
    const float* pl  = (const float*)d_in[8];
    const float* pm1 = (const float*)d_in[9];
    const float* pm2 = (const float*)d_in[10];

    int n = in_sizes[0];  // B = 4194304 (even)
    vfloat4* out = (vfloat4*)d_out;

    int block = 256;
    int hn = n >> 1;
    int grid = (hn + block - 1) / block;
    cartpole_rk4_kernel<<<grid, block, 0, stream>>>(
        x, v, th, om, u, pI, pb, pd, pl, pm1, pm2, out, n);
}

// Round 12
// 27.726 us; speedup vs baseline: 1.1257x; 1.0210x over previous
//
#include <hip/hip_runtime.h>
#include <math.h>

#define DT    0.019999999552965164f
#define GRAV  9.8100004196167f
#define GEAR  100.0f

// Best measured variant (R2, 27.65 us): one element per thread, 5 scalar
// coalesced dword loads (4B/lane), one lane-contiguous float4 store
// (16B/lane). All attempts to improve on this shape (float4 loads + strided
// or LDS-transposed stores, nt-store, grid-stride, 2-stream ILP) measured
// 28.3-33 us. 27.65 us = 5.3 TB/s mixed traffic ~= 84% of the measured
// 6.29 TB/s D2D ceiling on this chip -> practical memory roofline.
__global__ __launch_bounds__(256) void cartpole_rk4_kernel(
    const float* __restrict__ x,
    const float* __restrict__ v,
    const float* __restrict__ th,
    const float* __restrict__ om,
    const float* __restrict__ u,
    const float* __restrict__ pI,
    const float* __restrict__ pb,
    const float* __restrict__ pd,
    const float* __restrict__ pl,
    const float* __restrict__ pm1,
    const float* __restrict__ pm2,
    float4* __restrict__ out,
    int n)
{
    int i = blockIdx.x * blockDim.x + threadIdx.x;
    if (i >= n) return;

    // uniform physical parameters
    const float I  = pI[0];
    const float b  = pb[0];
    const float d  = pd[0];
    const float l  = pl[0];
    const float m1 = pm1[0];
    const float m2 = pm2[0];

    const float M     = m1 + m2;
    const float m2l   = m2 * l;
    const float Ieff  = I + m2l * l;        // I + m2*l*l
    const float m2gl  = m2l * GRAV;         // m2*g*l
    const float IeffM = Ieff * M;

    const float x0 = x[i];
    const float v0 = v[i];
    const float t0 = th[i];
    const float o0 = om[i];
    const float F  = GEAR * u[i];

    auto deriv = [&](float v_, float t_, float o_, float& xdd, float& tdd) {
        float s, c;
        __sincosf(t_, &s, &c);
        float A    = F - b * v_ + m2l * o_ * o_ * s;
        float Bq   = m2gl * s - d * o_;
        float mlc  = m2l * c;
        float D    = IeffM - mlc * mlc;
        float invD = __builtin_amdgcn_rcpf(D);
        xdd = (Ieff * A - mlc * Bq) * invD;
        tdd = (M * Bq - mlc * A) * invD;
    };

    const float half = 0.5f * DT;

    // k1
    float k1v, k1o;
    deriv(v0, t0, o0, k1v, k1o);

    // k2
    float v2 = v0 + half * k1v;
    float t2 = t0 + half * o0;
    float o2 = o0 + half * k1o;
    float k2v, k2o;
    deriv(v2, t2, o2, k2v, k2o);

    // k3
    float v3 = v0 + half * k2v;
    float t3 = t0 + half * o2;
    float o3 = o0 + half * k2o;
    float k3v, k3o;
    deriv(v3, t3, o3, k3v, k3o);

    // k4
    float v4 = v0 + DT * k3v;
    float t4 = t0 + DT * o3;
    float o4 = o0 + DT * k3o;
    float k4v, k4o;
    deriv(v4, t4, o4, k4v, k4o);

    const float w = DT * (1.0f / 6.0f);

    float4 r;
    r.x = x0 + w * (v0  + 2.0f * v2  + 2.0f * v3  + v4);
    r.y = v0 + w * (k1v + 2.0f * k2v + 2.0f * k3v + k4v);
    r.z = t0 + w * (o0  + 2.0f * o2  + 2.0f * o3  + o4);
    r.w = o0 + w * (k1o + 2.0f * k2o + 2.0f * k3o + k4o);

    out[i] = r;
}

extern "C" void kernel_launch(void* const* d_in, const int* in_sizes, int n_in,
                              void* d_out, int out_size, void* d_ws, size_t ws_size,
                              hipStream_t stream) {
    const float* x   = (const float*)d_in[0];
    const float* v   = (const float*)d_in[1];
    const float* th  = (const float*)d_in[2];
    const float* om  = (const float*)d_in[3];
    const float* u   = (const float*)d_in[4];
    const float* pI  = (const float*)d_in[5];
    const float* pb  = (const float*)d_in[6];
    const float* pd  = (const float*)d_in[7];
    const float* pl  = (const float*)d_in[8];
    const float* pm1 = (const float*)d_in[9];
    const float* pm2 = (const float*)d_in[10];

    int n = in_sizes[0];  // B = 4194304
    float4* out = (float4*)d_out;

    int block = 256;
    int grid = (n + block - 1) / block;
    cartpole_rk4_kernel<<<grid, block, 0, stream>>>(
        x, v, th, om, u, pI, pb, pd, pl, pm1, pm2, out, n);
}